// Round 7
// baseline (1428.697 us; speedup 1.0000x reference)
//
#include <hip/hip_runtime.h>
#include <hip/hip_bf16.h>

constexpr int D_ = 64;
constexpr int NN = 100000;
constexpr int NE = 1600000;
constexpr int NBLK = (NN + 1023) / 1024;  // 98
constexpr int NBKT = 8;                   // node buckets (1 per XCD)
constexpr int BSZ = NN / NBKT;            // 12500 nodes/bucket (exact)
constexpr int MCH = 4;                    // edge chunks per bucket
constexpr int NQ = NE / 4;                // 400000 quads of 4 edges

__device__ __forceinline__ float bflo(unsigned v) { return __uint_as_float(v << 16); }
__device__ __forceinline__ float bfhi(unsigned v) { return __uint_as_float(v & 0xffff0000u); }

// ---- bucketed count/fill: LDS histogram per (bucket, chunk) block.
// FILL=false: accumulate per-node counts into cnt (aggregated global atomics).
// FILL=true : claim per-node ranges from cur, then place entries via LDS cursors;
//             stores land in the bucket's contiguous offs window (XCD-local L2).
template <bool FILL>
__global__ __launch_bounds__(256) void k_bucket(const int* __restrict__ edges,
                                                int* __restrict__ cc,
                                                int* __restrict__ nbr) {
  const int bkt = blockIdx.x & (NBKT - 1);  // blockIdx%8 -> XCD affinity
  const int m = blockIdx.x >> 3;
  const int lo = bkt * BSZ;
  __shared__ int h[BSZ];
  for (int i = threadIdx.x; i < BSZ; i += 256) h[i] = 0;
  __syncthreads();
  const int q0 = m * (NQ / MCH), q1 = q0 + NQ / MCH;
  // pass 1: LDS histogram of in-bucket endpoints
  for (int base = q0; base < q1; base += 256 * 8) {
    int4 ea[8], eb[8];
    int ok[8];
#pragma unroll
    for (int u = 0; u < 8; ++u) {
      int q = base + u * 256 + (int)threadIdx.x;
      ok[u] = (q < q1);
      if (ok[u]) {
        const int4* ep = reinterpret_cast<const int4*>(edges + 8 * q);
        ea[u] = ep[0]; eb[u] = ep[1];
      }
    }
#pragma unroll
    for (int u = 0; u < 8; ++u) {
      if (!ok[u]) continue;
      int v;
      v = ea[u].x; if ((unsigned)(v - lo) < (unsigned)BSZ) atomicAdd(&h[v - lo], 1);
      v = ea[u].y; if ((unsigned)(v - lo) < (unsigned)BSZ) atomicAdd(&h[v - lo], 1);
      v = ea[u].z; if ((unsigned)(v - lo) < (unsigned)BSZ) atomicAdd(&h[v - lo], 1);
      v = ea[u].w; if ((unsigned)(v - lo) < (unsigned)BSZ) atomicAdd(&h[v - lo], 1);
      v = eb[u].x; if ((unsigned)(v - lo) < (unsigned)BSZ) atomicAdd(&h[v - lo], 1);
      v = eb[u].y; if ((unsigned)(v - lo) < (unsigned)BSZ) atomicAdd(&h[v - lo], 1);
      v = eb[u].z; if ((unsigned)(v - lo) < (unsigned)BSZ) atomicAdd(&h[v - lo], 1);
      v = eb[u].w; if ((unsigned)(v - lo) < (unsigned)BSZ) atomicAdd(&h[v - lo], 1);
    }
  }
  __syncthreads();
  // flush / claim: one aggregated global atomic per touched node
  for (int i = threadIdx.x; i < BSZ; i += 256) {
    int c = h[i];
    if (c) {
      int base = atomicAdd(&cc[lo + i], c);
      if (FILL) h[i] = base;  // h becomes the block's cursor for this node
    }
  }
  if (FILL) {
    __syncthreads();
    // pass 2: place entries at LDS-cursor positions
    for (int base = q0; base < q1; base += 256 * 8) {
      int4 ea[8], eb[8];
      int ok[8];
#pragma unroll
      for (int u = 0; u < 8; ++u) {
        int q = base + u * 256 + (int)threadIdx.x;
        ok[u] = (q < q1);
        if (ok[u]) {
          const int4* ep = reinterpret_cast<const int4*>(edges + 8 * q);
          ea[u] = ep[0]; eb[u] = ep[1];
        }
      }
#pragma unroll
      for (int u = 0; u < 8; ++u) {
        if (!ok[u]) continue;
        int s, d, p;
        s = ea[u].x; d = ea[u].y;
        if ((unsigned)(d - lo) < (unsigned)BSZ) { p = atomicAdd(&h[d - lo], 1); nbr[p] = s; }
        if ((unsigned)(s - lo) < (unsigned)BSZ) { p = atomicAdd(&h[s - lo], 1); nbr[p] = d; }
        s = ea[u].z; d = ea[u].w;
        if ((unsigned)(d - lo) < (unsigned)BSZ) { p = atomicAdd(&h[d - lo], 1); nbr[p] = s; }
        if ((unsigned)(s - lo) < (unsigned)BSZ) { p = atomicAdd(&h[s - lo], 1); nbr[p] = d; }
        s = eb[u].x; d = eb[u].y;
        if ((unsigned)(d - lo) < (unsigned)BSZ) { p = atomicAdd(&h[d - lo], 1); nbr[p] = s; }
        if ((unsigned)(s - lo) < (unsigned)BSZ) { p = atomicAdd(&h[s - lo], 1); nbr[p] = d; }
        s = eb[u].z; d = eb[u].w;
        if ((unsigned)(d - lo) < (unsigned)BSZ) { p = atomicAdd(&h[d - lo], 1); nbr[p] = s; }
        if ((unsigned)(s - lo) < (unsigned)BSZ) { p = atomicAdd(&h[s - lo], 1); nbr[p] = d; }
      }
    }
  }
}

// ---- hierarchical scan A: per-block exclusive scan, emit block totals
__global__ __launch_bounds__(1024) void k_scanA(const int* __restrict__ cnt,
                                                int* __restrict__ offs,
                                                int* __restrict__ bsum, int n) {
  __shared__ int sd[1024];
  const int tid = threadIdx.x;
  const int i = blockIdx.x * 1024 + tid;
  int v = (i < n) ? cnt[i] : 0;
  sd[tid] = v;
  __syncthreads();
  for (int off = 1; off < 1024; off <<= 1) {
    int t = (tid >= off) ? sd[tid - off] : 0;
    __syncthreads();
    sd[tid] += t;
    __syncthreads();
  }
  if (i < n) offs[i] = sd[tid] - v;
  if (tid == 1023) bsum[blockIdx.x] = sd[1023];
}

// ---- scan B: single block scans block totals; writes offs[n]=grand total
__global__ __launch_bounds__(128) void k_scanB(int* __restrict__ bsum,
                                               int* __restrict__ offs, int n, int nb) {
  __shared__ int sd[128];
  const int tid = threadIdx.x;
  int v = (tid < nb) ? bsum[tid] : 0;
  sd[tid] = v;
  __syncthreads();
  for (int off = 1; off < 128; off <<= 1) {
    int t = (tid >= off) ? sd[tid - off] : 0;
    __syncthreads();
    sd[tid] += t;
    __syncthreads();
  }
  if (tid < nb) bsum[tid] = sd[tid] - v;
  if (tid == 127) offs[n] = sd[127];
}

// ---- scan C: add block base; init fill cursor
__global__ __launch_bounds__(256) void k_scanC(int* __restrict__ offs,
                                               const int* __restrict__ bsum,
                                               int* __restrict__ cur, int n) {
  int i = blockIdx.x * 256 + threadIdx.x;
  if (i < n) {
    int o = offs[i] + bsum[i >> 10];
    offs[i] = o;
    cur[i] = o;
  }
}

// W staged transposed+padded: wT[j*68+k] = W[k*64+j]
__device__ __forceinline__ void stage_w(const float* __restrict__ W, float* wT) {
  for (int i = threadIdx.x; i < 4096; i += 256) {
    int k = i >> 6, j = i & 63;
    wT[j * 68 + k] = W[i];
  }
}

// ---- one streaming pass: base = h@W0+b0 (f32), msg = bf16(h@W1+b1)
__global__ __launch_bounds__(256) void k_gemm2(
    const float* __restrict__ h, const float* __restrict__ W0,
    const float* __restrict__ b0, const float* __restrict__ W1,
    const float* __restrict__ b1, float* __restrict__ base,
    __hip_bfloat16* __restrict__ msg, int nrows) {
  __shared__ float w0T[64 * 68];
  __shared__ float w1T[64 * 68];
  stage_w(W0, w0T);
  stage_w(W1, w1T);
  __syncthreads();
  const int lane = threadIdx.x & 63;
  const int wid = (blockIdx.x * 256 + threadIdx.x) >> 6;
  const int nw = (gridDim.x * 256) >> 6;
  const float bv0 = b0[lane], bv1 = b1[lane];
  const float4* wl0 = reinterpret_cast<const float4*>(&w0T[lane * 68]);
  const float4* wl1 = reinterpret_cast<const float4*>(&w1T[lane * 68]);
  for (int r = wid; r < nrows; r += nw) {
    const float4* hr = reinterpret_cast<const float4*>(h + (size_t)r * 64);
    float a0 = bv0, a1 = bv1;
#pragma unroll
    for (int k4 = 0; k4 < 16; ++k4) {
      float4 hv = hr[k4];
      float4 v0 = wl0[k4];
      float4 v1 = wl1[k4];
      a0 = fmaf(hv.x, v0.x, a0); a1 = fmaf(hv.x, v1.x, a1);
      a0 = fmaf(hv.y, v0.y, a0); a1 = fmaf(hv.y, v1.y, a1);
      a0 = fmaf(hv.z, v0.z, a0); a1 = fmaf(hv.z, v1.z, a1);
      a0 = fmaf(hv.w, v0.w, a0); a1 = fmaf(hv.w, v1.w, a1);
    }
    base[(size_t)r * 64 + lane] = a0;
    msg[(size_t)r * 64 + lane] = __float2bfloat16(a1);
  }
}

// ---- gather: half-wave pair loads (2 neighbor rows per instruction)
template <bool LN>
__global__ __launch_bounds__(256) void k_agg(
    const float* __restrict__ base, const __hip_bfloat16* __restrict__ msg,
    const int* __restrict__ offs, const int* __restrict__ nbr,
    const float* __restrict__ gamma, const float* __restrict__ beta,
    float* __restrict__ out, int nrows) {
  const int lane = threadIdx.x & 63;
  const int half = lane >> 5;
  const int c = lane & 31;
  const int wid = (blockIdx.x * 256 + threadIdx.x) >> 6;
  const int nw = (gridDim.x * 256) >> 6;
  float gm = 1.0f, bt = 0.0f;
  if (LN) { gm = gamma[lane]; bt = beta[lane]; }
  const unsigned* msg32 = reinterpret_cast<const unsigned*>(msg);
  for (int r = wid; r < nrows; r += nw) {
    const int n0 = offs[r], n1 = offs[r + 1];
    const float bval = base[(size_t)r * 64 + lane];
    float agx = 0.0f, agy = 0.0f;
    int j = n0;
    for (; j + 32 <= n1; j += 32) {
      int idx[16];
#pragma unroll
      for (int u = 0; u < 16; ++u) idx[u] = nbr[j + 2 * u + half];
      unsigned mv[16];
#pragma unroll
      for (int u = 0; u < 16; ++u) mv[u] = msg32[(idx[u] << 5) + c];
#pragma unroll
      for (int u = 0; u < 16; ++u) { agx += bflo(mv[u]); agy += bfhi(mv[u]); }
    }
    for (; j + 8 <= n1; j += 8) {
      int idx[4];
#pragma unroll
      for (int u = 0; u < 4; ++u) idx[u] = nbr[j + 2 * u + half];
      unsigned mv[4];
#pragma unroll
      for (int u = 0; u < 4; ++u) mv[u] = msg32[(idx[u] << 5) + c];
#pragma unroll
      for (int u = 0; u < 4; ++u) { agx += bflo(mv[u]); agy += bfhi(mv[u]); }
    }
    for (; j + 2 <= n1; j += 2) {
      unsigned mv = msg32[(nbr[j + half] << 5) + c];
      agx += bflo(mv); agy += bfhi(mv);
    }
    agx += __shfl_xor(agx, 32, 64);
    agy += __shfl_xor(agy, 32, 64);
    float tx = __shfl(agx, lane >> 1, 64);
    float ty = __shfl(agy, lane >> 1, 64);
    float ag = (lane & 1) ? ty : tx;
    for (; j < n1; ++j)
      ag += __bfloat162float(msg[((int)nbr[j] << 6) + lane]);
    const float rdeg = 1.0f / fmaxf((float)(n1 - n0), 1.0f);
    float val = fmaf(ag, rdeg, bval);
    if (LN) {
      float s = val;
#pragma unroll
      for (int off = 32; off > 0; off >>= 1) s += __shfl_xor(s, off, 64);
      const float mu = s * (1.0f / 64.0f);
      const float dv = val - mu;
      float v2 = dv * dv;
#pragma unroll
      for (int off = 32; off > 0; off >>= 1) v2 += __shfl_xor(v2, off, 64);
      const float var = v2 * (1.0f / 64.0f);
      val = fmaxf(fmaf(dv * rsqrtf(var + 1e-5f), gm, bt), 0.0f);
    }
    out[(size_t)r * 64 + lane] = val;
  }
}

extern "C" void kernel_launch(void* const* d_in, const int* in_sizes, int n_in,
                              void* d_out, int out_size, void* d_ws, size_t ws_size,
                              hipStream_t stream) {
  const float* vert = (const float*)d_in[0];
  const int* edges = (const int*)d_in[1];
  const float* W0 = (const float*)d_in[2];
  const float* b0 = (const float*)d_in[3];
  const float* W1 = (const float*)d_in[4];
  const float* b1 = (const float*)d_in[5];
  const float* lng = (const float*)d_in[6];
  const float* lnb = (const float*)d_in[7];
  float* base = (float*)d_out;  // base buffer lives in d_out all layers

  const size_t HB = (size_t)NN * D_ * sizeof(float);  // 25.6 MB
  float* hbuf = (float*)d_ws;
  int* nbr = (int*)((char*)d_ws + HB);                              // 12.8 MB
  __hip_bfloat16* msg = (__hip_bfloat16*)((char*)d_ws + HB + (size_t)2 * NE * 4);
  int* cnt = (int*)msg;  // CSR-build only (dead before msg is written)
  int* bsum = cnt + NN;
  int* offs = (int*)((char*)d_ws + HB + (size_t)2 * NE * 4 + HB / 2);
  int* cur = cnt;  // cnt region reused as fill cursor

  // ---- CSR build (bucketed, transaction-minimized)
  hipMemsetAsync(cnt, 0, NN * sizeof(int), stream);
  k_bucket<false><<<NBKT * MCH, 256, 0, stream>>>(edges, cnt, nullptr);
  k_scanA<<<NBLK, 1024, 0, stream>>>(cnt, offs, bsum, NN);
  k_scanB<<<1, 128, 0, stream>>>(bsum, offs, NN, NBLK);
  k_scanC<<<(NN + 255) / 256, 256, 0, stream>>>(offs, bsum, cur, NN);
  k_bucket<true><<<NBKT * MCH, 256, 0, stream>>>(edges, cur, nbr);

  const int GB = 2048;

  for (int l = 0; l < 3; ++l) {
    const float* hcur = (l == 0) ? vert : hbuf;
    k_gemm2<<<GB, 256, 0, stream>>>(hcur, W0 + l * 4096, b0 + l * 64,
                                    W1 + l * 4096, b1 + l * 64, base, msg, NN);
    if (l < 2) {
      k_agg<true><<<GB, 256, 0, stream>>>(base, msg, offs, nbr,
                                          lng + l * 64, lnb + l * 64, hbuf, NN);
    } else {
      k_agg<false><<<GB, 256, 0, stream>>>(base, msg, offs, nbr,
                                           nullptr, nullptr, base, NN);
    }
  }
}

// Round 8
// 847.537 us; speedup vs baseline: 1.6857x; 1.6857x over previous
//
#include <hip/hip_runtime.h>
#include <hip/hip_bf16.h>

constexpr int D_ = 64;
constexpr int NN = 100000;
constexpr int NE = 1600000;
constexpr int NBLK = (NN + 1023) / 1024;  // 98

__device__ __forceinline__ float bflo(unsigned v) { return __uint_as_float(v << 16); }
__device__ __forceinline__ float bfhi(unsigned v) { return __uint_as_float(v & 0xffff0000u); }

// ---- rank pass: one atomic per endpoint; returned rank stored coalesced.
// Endpoint order per edge (s,d): entry 2e+0 -> node d (stores s), 2e+1 -> node s.
__global__ __launch_bounds__(256) void k_rank(const int* __restrict__ edges,
                                              int* __restrict__ cnt,
                                              ushort* __restrict__ rank, int nq) {
  int t = blockIdx.x * 256 + threadIdx.x;
  if (t >= nq) return;
  const int4* ep = reinterpret_cast<const int4*>(edges + 8 * t);
  int4 e01 = ep[0], e23 = ep[1];  // (s0,d0,s1,d1), (s2,d2,s3,d3)
  int r0 = atomicAdd(cnt + e01.y, 1);
  int r1 = atomicAdd(cnt + e01.x, 1);
  int r2 = atomicAdd(cnt + e01.w, 1);
  int r3 = atomicAdd(cnt + e01.z, 1);
  int r4 = atomicAdd(cnt + e23.y, 1);
  int r5 = atomicAdd(cnt + e23.x, 1);
  int r6 = atomicAdd(cnt + e23.w, 1);
  int r7 = atomicAdd(cnt + e23.z, 1);
  uint4 pk;
  pk.x = (unsigned)r0 | ((unsigned)r1 << 16);
  pk.y = (unsigned)r2 | ((unsigned)r3 << 16);
  pk.z = (unsigned)r4 | ((unsigned)r5 << 16);
  pk.w = (unsigned)r6 | ((unsigned)r7 << 16);
  reinterpret_cast<uint4*>(rank)[t] = pk;  // coalesced 16B
}

// ---- hierarchical scan A: per-block exclusive scan, emit block totals
__global__ __launch_bounds__(1024) void k_scanA(const int* __restrict__ cnt,
                                                int* __restrict__ offs,
                                                int* __restrict__ bsum, int n) {
  __shared__ int sd[1024];
  const int tid = threadIdx.x;
  const int i = blockIdx.x * 1024 + tid;
  int v = (i < n) ? cnt[i] : 0;
  sd[tid] = v;
  __syncthreads();
  for (int off = 1; off < 1024; off <<= 1) {
    int t = (tid >= off) ? sd[tid - off] : 0;
    __syncthreads();
    sd[tid] += t;
    __syncthreads();
  }
  if (i < n) offs[i] = sd[tid] - v;
  if (tid == 1023) bsum[blockIdx.x] = sd[1023];
}

// ---- scan B: single block scans block totals; writes offs[n]=grand total
__global__ __launch_bounds__(128) void k_scanB(int* __restrict__ bsum,
                                               int* __restrict__ offs, int n, int nb) {
  __shared__ int sd[128];
  const int tid = threadIdx.x;
  int v = (tid < nb) ? bsum[tid] : 0;
  sd[tid] = v;
  __syncthreads();
  for (int off = 1; off < 128; off <<= 1) {
    int t = (tid >= off) ? sd[tid - off] : 0;
    __syncthreads();
    sd[tid] += t;
    __syncthreads();
  }
  if (tid < nb) bsum[tid] = sd[tid] - v;
  if (tid == 127) offs[n] = sd[127];
}

// ---- scan C: add block base (offs finalized in place)
__global__ __launch_bounds__(256) void k_scanC(int* __restrict__ offs,
                                               const int* __restrict__ bsum, int n) {
  int i = blockIdx.x * 256 + threadIdx.x;
  if (i < n) offs[i] += bsum[i >> 10];
}

// ---- place pass: no atomics; slot = offs[node] + rank
__global__ __launch_bounds__(256) void k_place(const int* __restrict__ edges,
                                               const ushort* __restrict__ rank,
                                               const int* __restrict__ offs,
                                               int* __restrict__ nbr, int nq) {
  int t = blockIdx.x * 256 + threadIdx.x;
  if (t >= nq) return;
  const int4* ep = reinterpret_cast<const int4*>(edges + 8 * t);
  int4 e01 = ep[0], e23 = ep[1];
  uint4 pk = reinterpret_cast<const uint4*>(rank)[t];
  // issue all 8 offs loads (L2-resident), then all 8 stores
  int o0 = offs[e01.y], o1 = offs[e01.x], o2 = offs[e01.w], o3 = offs[e01.z];
  int o4 = offs[e23.y], o5 = offs[e23.x], o6 = offs[e23.w], o7 = offs[e23.z];
  nbr[o0 + (pk.x & 0xffff)] = e01.x;
  nbr[o1 + (pk.x >> 16)]    = e01.y;
  nbr[o2 + (pk.y & 0xffff)] = e01.z;
  nbr[o3 + (pk.y >> 16)]    = e01.w;
  nbr[o4 + (pk.z & 0xffff)] = e23.x;
  nbr[o5 + (pk.z >> 16)]    = e23.y;
  nbr[o6 + (pk.w & 0xffff)] = e23.z;
  nbr[o7 + (pk.w >> 16)]    = e23.w;
}

// W staged transposed+padded: wT[j*68+k] = W[k*64+j]
__device__ __forceinline__ void stage_w(const float* __restrict__ W, float* wT) {
  for (int i = threadIdx.x; i < 4096; i += 256) {
    int k = i >> 6, j = i & 63;
    wT[j * 68 + k] = W[i];
  }
}

// ---- one streaming pass: base = h@W0+b0 (f32), msg = bf16(h@W1+b1)
__global__ __launch_bounds__(256) void k_gemm2(
    const float* __restrict__ h, const float* __restrict__ W0,
    const float* __restrict__ b0, const float* __restrict__ W1,
    const float* __restrict__ b1, float* __restrict__ base,
    __hip_bfloat16* __restrict__ msg, int nrows) {
  __shared__ float w0T[64 * 68];
  __shared__ float w1T[64 * 68];
  stage_w(W0, w0T);
  stage_w(W1, w1T);
  __syncthreads();
  const int lane = threadIdx.x & 63;
  const int wid = (blockIdx.x * 256 + threadIdx.x) >> 6;
  const int nw = (gridDim.x * 256) >> 6;
  const float bv0 = b0[lane], bv1 = b1[lane];
  const float4* wl0 = reinterpret_cast<const float4*>(&w0T[lane * 68]);
  const float4* wl1 = reinterpret_cast<const float4*>(&w1T[lane * 68]);
  for (int r = wid; r < nrows; r += nw) {
    const float4* hr = reinterpret_cast<const float4*>(h + (size_t)r * 64);
    float a0 = bv0, a1 = bv1;
#pragma unroll
    for (int k4 = 0; k4 < 16; ++k4) {
      float4 hv = hr[k4];
      float4 v0 = wl0[k4];
      float4 v1 = wl1[k4];
      a0 = fmaf(hv.x, v0.x, a0); a1 = fmaf(hv.x, v1.x, a1);
      a0 = fmaf(hv.y, v0.y, a0); a1 = fmaf(hv.y, v1.y, a1);
      a0 = fmaf(hv.z, v0.z, a0); a1 = fmaf(hv.z, v1.z, a1);
      a0 = fmaf(hv.w, v0.w, a0); a1 = fmaf(hv.w, v1.w, a1);
    }
    base[(size_t)r * 64 + lane] = a0;
    msg[(size_t)r * 64 + lane] = __float2bfloat16(a1);
  }
}

// ---- gather: half-wave pair loads (2 neighbor rows per instruction)
template <bool LN>
__global__ __launch_bounds__(256) void k_agg(
    const float* __restrict__ base, const __hip_bfloat16* __restrict__ msg,
    const int* __restrict__ offs, const int* __restrict__ nbr,
    const float* __restrict__ gamma, const float* __restrict__ beta,
    float* __restrict__ out, int nrows) {
  const int lane = threadIdx.x & 63;
  const int half = lane >> 5;
  const int c = lane & 31;
  const int wid = (blockIdx.x * 256 + threadIdx.x) >> 6;
  const int nw = (gridDim.x * 256) >> 6;
  float gm = 1.0f, bt = 0.0f;
  if (LN) { gm = gamma[lane]; bt = beta[lane]; }
  const unsigned* msg32 = reinterpret_cast<const unsigned*>(msg);
  for (int r = wid; r < nrows; r += nw) {
    const int n0 = offs[r], n1 = offs[r + 1];
    const float bval = base[(size_t)r * 64 + lane];
    float agx = 0.0f, agy = 0.0f;
    int j = n0;
    for (; j + 32 <= n1; j += 32) {
      int idx[16];
#pragma unroll
      for (int u = 0; u < 16; ++u) idx[u] = nbr[j + 2 * u + half];
      unsigned mv[16];
#pragma unroll
      for (int u = 0; u < 16; ++u) mv[u] = msg32[(idx[u] << 5) + c];
#pragma unroll
      for (int u = 0; u < 16; ++u) { agx += bflo(mv[u]); agy += bfhi(mv[u]); }
    }
    for (; j + 8 <= n1; j += 8) {
      int idx[4];
#pragma unroll
      for (int u = 0; u < 4; ++u) idx[u] = nbr[j + 2 * u + half];
      unsigned mv[4];
#pragma unroll
      for (int u = 0; u < 4; ++u) mv[u] = msg32[(idx[u] << 5) + c];
#pragma unroll
      for (int u = 0; u < 4; ++u) { agx += bflo(mv[u]); agy += bfhi(mv[u]); }
    }
    for (; j + 2 <= n1; j += 2) {
      unsigned mv = msg32[(nbr[j + half] << 5) + c];
      agx += bflo(mv); agy += bfhi(mv);
    }
    agx += __shfl_xor(agx, 32, 64);
    agy += __shfl_xor(agy, 32, 64);
    float tx = __shfl(agx, lane >> 1, 64);
    float ty = __shfl(agy, lane >> 1, 64);
    float ag = (lane & 1) ? ty : tx;
    for (; j < n1; ++j)
      ag += __bfloat162float(msg[((int)nbr[j] << 6) + lane]);
    const float rdeg = 1.0f / fmaxf((float)(n1 - n0), 1.0f);
    float val = fmaf(ag, rdeg, bval);
    if (LN) {
      float s = val;
#pragma unroll
      for (int off = 32; off > 0; off >>= 1) s += __shfl_xor(s, off, 64);
      const float mu = s * (1.0f / 64.0f);
      const float dv = val - mu;
      float v2 = dv * dv;
#pragma unroll
      for (int off = 32; off > 0; off >>= 1) v2 += __shfl_xor(v2, off, 64);
      const float var = v2 * (1.0f / 64.0f);
      val = fmaxf(fmaf(dv * rsqrtf(var + 1e-5f), gm, bt), 0.0f);
    }
    out[(size_t)r * 64 + lane] = val;
  }
}

extern "C" void kernel_launch(void* const* d_in, const int* in_sizes, int n_in,
                              void* d_out, int out_size, void* d_ws, size_t ws_size,
                              hipStream_t stream) {
  const float* vert = (const float*)d_in[0];
  const int* edges = (const int*)d_in[1];
  const float* W0 = (const float*)d_in[2];
  const float* b0 = (const float*)d_in[3];
  const float* W1 = (const float*)d_in[4];
  const float* b1 = (const float*)d_in[5];
  const float* lng = (const float*)d_in[6];
  const float* lnb = (const float*)d_in[7];
  float* base = (float*)d_out;  // base buffer lives in d_out all layers

  const size_t HB = (size_t)NN * D_ * sizeof(float);  // 25.6 MB
  float* hbuf = (float*)d_ws;
  int* nbr = (int*)((char*)d_ws + HB);  // 12.8 MB
  char* msgreg = (char*)d_ws + HB + (size_t)2 * NE * 4;  // 12.8 MB region
  __hip_bfloat16* msg = (__hip_bfloat16*)msgreg;
  // CSR-build temporaries alias the msg region (dead before gemm2 writes msg)
  ushort* rank = (ushort*)msgreg;                      // 6.4 MB
  int* cnt = (int*)(msgreg + (size_t)2 * NE * 2);      // 400 KB
  int* bsum = cnt + NN;                                // 392 B
  int* offs = (int*)((char*)d_ws + HB + (size_t)2 * NE * 4 + HB / 2);  // persistent

  const int NQ4 = NE / 4;  // 400000 threads, 4 edges (8 endpoints) each

  // ---- CSR build: rank-merge (one atomic pass, one atomic-free place pass)
  hipMemsetAsync(cnt, 0, NN * sizeof(int), stream);
  k_rank<<<(NQ4 + 255) / 256, 256, 0, stream>>>(edges, cnt, rank, NQ4);
  k_scanA<<<NBLK, 1024, 0, stream>>>(cnt, offs, bsum, NN);
  k_scanB<<<1, 128, 0, stream>>>(bsum, offs, NN, NBLK);
  k_scanC<<<(NN + 255) / 256, 256, 0, stream>>>(offs, bsum, NN);
  k_place<<<(NQ4 + 255) / 256, 256, 0, stream>>>(edges, rank, offs, nbr, NQ4);

  const int GB = 2048;

  for (int l = 0; l < 3; ++l) {
    const float* hcur = (l == 0) ? vert : hbuf;
    k_gemm2<<<GB, 256, 0, stream>>>(hcur, W0 + l * 4096, b0 + l * 64,
                                    W1 + l * 4096, b1 + l * 64, base, msg, NN);
    if (l < 2) {
      k_agg<true><<<GB, 256, 0, stream>>>(base, msg, offs, nbr,
                                          lng + l * 64, lnb + l * 64, hbuf, NN);
    } else {
      k_agg<false><<<GB, 256, 0, stream>>>(base, msg, offs, nbr,
                                           nullptr, nullptr, base, NN);
    }
  }
}

// Round 9
// 809.291 us; speedup vs baseline: 1.7654x; 1.0473x over previous
//
#include <hip/hip_runtime.h>
#include <hip/hip_bf16.h>

constexpr int D_ = 64;
constexpr int NN = 100000;
constexpr int NE = 1600000;
constexpr int NBLK = (NN + 1023) / 1024;  // 98
constexpr int RB = 8;                     // rows per wave-batch in gemm2

__device__ __forceinline__ float bflo(unsigned v) { return __uint_as_float(v << 16); }
__device__ __forceinline__ float bfhi(unsigned v) { return __uint_as_float(v & 0xffff0000u); }

// ---- rank pass: one atomic per endpoint; returned rank stored coalesced.
__global__ __launch_bounds__(256) void k_rank(const int* __restrict__ edges,
                                              int* __restrict__ cnt,
                                              ushort* __restrict__ rank, int nq) {
  int t = blockIdx.x * 256 + threadIdx.x;
  if (t >= nq) return;
  const int4* ep = reinterpret_cast<const int4*>(edges + 8 * t);
  int4 e01 = ep[0], e23 = ep[1];  // (s0,d0,s1,d1), (s2,d2,s3,d3)
  int r0 = atomicAdd(cnt + e01.y, 1);
  int r1 = atomicAdd(cnt + e01.x, 1);
  int r2 = atomicAdd(cnt + e01.w, 1);
  int r3 = atomicAdd(cnt + e01.z, 1);
  int r4 = atomicAdd(cnt + e23.y, 1);
  int r5 = atomicAdd(cnt + e23.x, 1);
  int r6 = atomicAdd(cnt + e23.w, 1);
  int r7 = atomicAdd(cnt + e23.z, 1);
  uint4 pk;
  pk.x = (unsigned)r0 | ((unsigned)r1 << 16);
  pk.y = (unsigned)r2 | ((unsigned)r3 << 16);
  pk.z = (unsigned)r4 | ((unsigned)r5 << 16);
  pk.w = (unsigned)r6 | ((unsigned)r7 << 16);
  reinterpret_cast<uint4*>(rank)[t] = pk;  // coalesced 16B
}

// ---- hierarchical scan A
__global__ __launch_bounds__(1024) void k_scanA(const int* __restrict__ cnt,
                                                int* __restrict__ offs,
                                                int* __restrict__ bsum, int n) {
  __shared__ int sd[1024];
  const int tid = threadIdx.x;
  const int i = blockIdx.x * 1024 + tid;
  int v = (i < n) ? cnt[i] : 0;
  sd[tid] = v;
  __syncthreads();
  for (int off = 1; off < 1024; off <<= 1) {
    int t = (tid >= off) ? sd[tid - off] : 0;
    __syncthreads();
    sd[tid] += t;
    __syncthreads();
  }
  if (i < n) offs[i] = sd[tid] - v;
  if (tid == 1023) bsum[blockIdx.x] = sd[1023];
}

// ---- scan B
__global__ __launch_bounds__(128) void k_scanB(int* __restrict__ bsum,
                                               int* __restrict__ offs, int n, int nb) {
  __shared__ int sd[128];
  const int tid = threadIdx.x;
  int v = (tid < nb) ? bsum[tid] : 0;
  sd[tid] = v;
  __syncthreads();
  for (int off = 1; off < 128; off <<= 1) {
    int t = (tid >= off) ? sd[tid - off] : 0;
    __syncthreads();
    sd[tid] += t;
    __syncthreads();
  }
  if (tid < nb) bsum[tid] = sd[tid] - v;
  if (tid == 127) offs[n] = sd[127];
}

// ---- scan C
__global__ __launch_bounds__(256) void k_scanC(int* __restrict__ offs,
                                               const int* __restrict__ bsum, int n) {
  int i = blockIdx.x * 256 + threadIdx.x;
  if (i < n) offs[i] += bsum[i >> 10];
}

// ---- place pass: no atomics; slot = offs[node] + rank
__global__ __launch_bounds__(256) void k_place(const int* __restrict__ edges,
                                               const ushort* __restrict__ rank,
                                               const int* __restrict__ offs,
                                               int* __restrict__ nbr, int nq) {
  int t = blockIdx.x * 256 + threadIdx.x;
  if (t >= nq) return;
  const int4* ep = reinterpret_cast<const int4*>(edges + 8 * t);
  int4 e01 = ep[0], e23 = ep[1];
  uint4 pk = reinterpret_cast<const uint4*>(rank)[t];
  int o0 = offs[e01.y], o1 = offs[e01.x], o2 = offs[e01.w], o3 = offs[e01.z];
  int o4 = offs[e23.y], o5 = offs[e23.x], o6 = offs[e23.w], o7 = offs[e23.z];
  nbr[o0 + (pk.x & 0xffff)] = e01.x;
  nbr[o1 + (pk.x >> 16)]    = e01.y;
  nbr[o2 + (pk.y & 0xffff)] = e01.z;
  nbr[o3 + (pk.y >> 16)]    = e01.w;
  nbr[o4 + (pk.z & 0xffff)] = e23.x;
  nbr[o5 + (pk.z >> 16)]    = e23.y;
  nbr[o6 + (pk.w & 0xffff)] = e23.z;
  nbr[o7 + (pk.w >> 16)]    = e23.w;
}

// W staged transposed+padded: wT[j*68+k] = W[k*64+j]
__device__ __forceinline__ void stage_w(const float* __restrict__ W, float* wT) {
  for (int i = threadIdx.x; i < 4096; i += 256) {
    int k = i >> 6, j = i & 63;
    wT[j * 68 + k] = W[i];
  }
}

// ---- gemm2: base = h@W0+b0 (f32), msg = bf16(h@W1+b1).
// Coalesced 8-row register staging -> wave-private LDS -> broadcast ds_read.
// k4-outer, 8-row-inner: W reads amortized 8x, acc fully in regs.
__global__ __launch_bounds__(256) void k_gemm2(
    const float* __restrict__ h, const float* __restrict__ W0,
    const float* __restrict__ b0, const float* __restrict__ W1,
    const float* __restrict__ b1, float* __restrict__ base,
    __hip_bfloat16* __restrict__ msg, int nrows) {
  __shared__ float w0T[64 * 68];
  __shared__ float w1T[64 * 68];
  __shared__ float rbuf[4][RB * 64];  // 8 KB: wave-private row tiles
  stage_w(W0, w0T);
  stage_w(W1, w1T);
  __syncthreads();
  const int lane = threadIdx.x & 63;
  const int wv = threadIdx.x >> 6;
  const int wid = (blockIdx.x * 256 + threadIdx.x) >> 6;
  const int nw = (gridDim.x * 256) >> 6;
  const float bv0 = b0[lane], bv1 = b1[lane];
  const float4* wl0 = reinterpret_cast<const float4*>(&w0T[lane * 68]);
  const float4* wl1 = reinterpret_cast<const float4*>(&w1T[lane * 68]);
  float* myrows = rbuf[wv];

  const int chunk = (nrows + nw - 1) / nw;
  const int r0 = wid * chunk;
  const int r1 = min(r0 + chunk, nrows);
  if (r0 >= nrows) return;

  // prologue: coalesced load of first batch (1 instr = 1 full row)
  float st[RB];
#pragma unroll
  for (int rr = 0; rr < RB; ++rr) {
    int r = min(r0 + rr, nrows - 1);
    st[rr] = h[(size_t)r * 64 + lane];
  }
  for (int rb = r0; rb < r1; rb += RB) {
    // park staged rows in LDS (wave-private; no barrier needed)
#pragma unroll
    for (int rr = 0; rr < RB; ++rr) myrows[rr * 64 + lane] = st[rr];
    // issue next batch's loads early (hide HBM/L2 latency under compute)
    const int nb = rb + RB;
    if (nb < r1) {
#pragma unroll
      for (int rr = 0; rr < RB; ++rr) {
        int r = min(nb + rr, nrows - 1);
        st[rr] = h[(size_t)r * 64 + lane];
      }
    }
    float a0[RB], a1[RB];
#pragma unroll
    for (int rr = 0; rr < RB; ++rr) { a0[rr] = bv0; a1[rr] = bv1; }
#pragma unroll
    for (int k4 = 0; k4 < 16; ++k4) {
      const float4 v0 = wl0[k4];  // per-lane W column slice (reused 8 rows)
      const float4 v1 = wl1[k4];
#pragma unroll
      for (int rr = 0; rr < RB; ++rr) {
        float4 hv = *reinterpret_cast<const float4*>(&myrows[rr * 64 + k4 * 4]);
        a0[rr] = fmaf(hv.x, v0.x, a0[rr]); a1[rr] = fmaf(hv.x, v1.x, a1[rr]);
        a0[rr] = fmaf(hv.y, v0.y, a0[rr]); a1[rr] = fmaf(hv.y, v1.y, a1[rr]);
        a0[rr] = fmaf(hv.z, v0.z, a0[rr]); a1[rr] = fmaf(hv.z, v1.z, a1[rr]);
        a0[rr] = fmaf(hv.w, v0.w, a0[rr]); a1[rr] = fmaf(hv.w, v1.w, a1[rr]);
      }
    }
#pragma unroll
    for (int rr = 0; rr < RB; ++rr) {
      int r = rb + rr;
      if (r < r1) {
        base[(size_t)r * 64 + lane] = a0[rr];
        msg[(size_t)r * 64 + lane] = __float2bfloat16(a1[rr]);
      }
    }
  }
}

// ---- gather: half-wave pair loads (2 neighbor rows per instruction)
template <bool LN>
__global__ __launch_bounds__(256) void k_agg(
    const float* __restrict__ base, const __hip_bfloat16* __restrict__ msg,
    const int* __restrict__ offs, const int* __restrict__ nbr,
    const float* __restrict__ gamma, const float* __restrict__ beta,
    float* __restrict__ out, int nrows) {
  const int lane = threadIdx.x & 63;
  const int half = lane >> 5;
  const int c = lane & 31;
  const int wid = (blockIdx.x * 256 + threadIdx.x) >> 6;
  const int nw = (gridDim.x * 256) >> 6;
  float gm = 1.0f, bt = 0.0f;
  if (LN) { gm = gamma[lane]; bt = beta[lane]; }
  const unsigned* msg32 = reinterpret_cast<const unsigned*>(msg);
  for (int r = wid; r < nrows; r += nw) {
    const int n0 = offs[r], n1 = offs[r + 1];
    const float bval = base[(size_t)r * 64 + lane];
    float agx = 0.0f, agy = 0.0f;
    int j = n0;
    for (; j + 32 <= n1; j += 32) {
      int idx[16];
#pragma unroll
      for (int u = 0; u < 16; ++u) idx[u] = nbr[j + 2 * u + half];
      unsigned mv[16];
#pragma unroll
      for (int u = 0; u < 16; ++u) mv[u] = msg32[(idx[u] << 5) + c];
#pragma unroll
      for (int u = 0; u < 16; ++u) { agx += bflo(mv[u]); agy += bfhi(mv[u]); }
    }
    for (; j + 8 <= n1; j += 8) {
      int idx[4];
#pragma unroll
      for (int u = 0; u < 4; ++u) idx[u] = nbr[j + 2 * u + half];
      unsigned mv[4];
#pragma unroll
      for (int u = 0; u < 4; ++u) mv[u] = msg32[(idx[u] << 5) + c];
#pragma unroll
      for (int u = 0; u < 4; ++u) { agx += bflo(mv[u]); agy += bfhi(mv[u]); }
    }
    for (; j + 2 <= n1; j += 2) {
      unsigned mv = msg32[(nbr[j + half] << 5) + c];
      agx += bflo(mv); agy += bfhi(mv);
    }
    agx += __shfl_xor(agx, 32, 64);
    agy += __shfl_xor(agy, 32, 64);
    float tx = __shfl(agx, lane >> 1, 64);
    float ty = __shfl(agy, lane >> 1, 64);
    float ag = (lane & 1) ? ty : tx;
    for (; j < n1; ++j)
      ag += __bfloat162float(msg[((int)nbr[j] << 6) + lane]);
    const float rdeg = 1.0f / fmaxf((float)(n1 - n0), 1.0f);
    float val = fmaf(ag, rdeg, bval);
    if (LN) {
      float s = val;
#pragma unroll
      for (int off = 32; off > 0; off >>= 1) s += __shfl_xor(s, off, 64);
      const float mu = s * (1.0f / 64.0f);
      const float dv = val - mu;
      float v2 = dv * dv;
#pragma unroll
      for (int off = 32; off > 0; off >>= 1) v2 += __shfl_xor(v2, off, 64);
      const float var = v2 * (1.0f / 64.0f);
      val = fmaxf(fmaf(dv * rsqrtf(var + 1e-5f), gm, bt), 0.0f);
    }
    out[(size_t)r * 64 + lane] = val;
  }
}

extern "C" void kernel_launch(void* const* d_in, const int* in_sizes, int n_in,
                              void* d_out, int out_size, void* d_ws, size_t ws_size,
                              hipStream_t stream) {
  const float* vert = (const float*)d_in[0];
  const int* edges = (const int*)d_in[1];
  const float* W0 = (const float*)d_in[2];
  const float* b0 = (const float*)d_in[3];
  const float* W1 = (const float*)d_in[4];
  const float* b1 = (const float*)d_in[5];
  const float* lng = (const float*)d_in[6];
  const float* lnb = (const float*)d_in[7];
  float* base = (float*)d_out;  // base buffer lives in d_out all layers

  const size_t HB = (size_t)NN * D_ * sizeof(float);  // 25.6 MB
  float* hbuf = (float*)d_ws;
  int* nbr = (int*)((char*)d_ws + HB);  // 12.8 MB
  char* msgreg = (char*)d_ws + HB + (size_t)2 * NE * 4;  // 12.8 MB region
  __hip_bfloat16* msg = (__hip_bfloat16*)msgreg;
  // CSR-build temporaries alias the msg region (dead before gemm2 writes msg)
  ushort* rank = (ushort*)msgreg;                      // 6.4 MB
  int* cnt = (int*)(msgreg + (size_t)2 * NE * 2);      // 400 KB
  int* bsum = cnt + NN;
  int* offs = (int*)((char*)d_ws + HB + (size_t)2 * NE * 4 + HB / 2);  // persistent

  const int NQ4 = NE / 4;

  // ---- CSR build: rank-merge (one atomic pass, one atomic-free place pass)
  hipMemsetAsync(cnt, 0, NN * sizeof(int), stream);
  k_rank<<<(NQ4 + 255) / 256, 256, 0, stream>>>(edges, cnt, rank, NQ4);
  k_scanA<<<NBLK, 1024, 0, stream>>>(cnt, offs, bsum, NN);
  k_scanB<<<1, 128, 0, stream>>>(bsum, offs, NN, NBLK);
  k_scanC<<<(NN + 255) / 256, 256, 0, stream>>>(offs, bsum, NN);
  k_place<<<(NQ4 + 255) / 256, 256, 0, stream>>>(edges, rank, offs, nbr, NQ4);

  const int GB = 2048;   // agg grid
  const int GG = 512;    // gemm2 grid: 2048 waves, ~49 rows each, 7-deep pipeline

  for (int l = 0; l < 3; ++l) {
    const float* hcur = (l == 0) ? vert : hbuf;
    k_gemm2<<<GG, 256, 0, stream>>>(hcur, W0 + l * 4096, b0 + l * 64,
                                    W1 + l * 4096, b1 + l * 64, base, msg, NN);
    if (l < 2) {
      k_agg<true><<<GB, 256, 0, stream>>>(base, msg, offs, nbr,
                                          lng + l * 64, lnb + l * 64, hbuf, NN);
    } else {
      k_agg<false><<<GB, 256, 0, stream>>>(base, msg, offs, nbr,
                                           nullptr, nullptr, base, NN);
    }
  }
}

// Round 10
// 573.911 us; speedup vs baseline: 2.4894x; 1.4101x over previous
//
#include <hip/hip_runtime.h>
#include <hip/hip_bf16.h>

constexpr int D_ = 64;
constexpr int NN = 100000;
constexpr int NE = 1600000;
constexpr int NBLK = (NN + 1023) / 1024;  // 98
constexpr int RB = 8;                     // rows per wave-batch in gemm2

__device__ __forceinline__ float bflo(unsigned v) { return __uint_as_float(v << 16); }
__device__ __forceinline__ float bfhi(unsigned v) { return __uint_as_float(v & 0xffff0000u); }

// ---- rank pass: one atomic per endpoint; returned rank stored coalesced.
__global__ __launch_bounds__(256) void k_rank(const int* __restrict__ edges,
                                              int* __restrict__ cnt,
                                              ushort* __restrict__ rank, int nq) {
  int t = blockIdx.x * 256 + threadIdx.x;
  if (t >= nq) return;
  const int4* ep = reinterpret_cast<const int4*>(edges + 8 * t);
  int4 e01 = ep[0], e23 = ep[1];  // (s0,d0,s1,d1), (s2,d2,s3,d3)
  int r0 = atomicAdd(cnt + e01.y, 1);
  int r1 = atomicAdd(cnt + e01.x, 1);
  int r2 = atomicAdd(cnt + e01.w, 1);
  int r3 = atomicAdd(cnt + e01.z, 1);
  int r4 = atomicAdd(cnt + e23.y, 1);
  int r5 = atomicAdd(cnt + e23.x, 1);
  int r6 = atomicAdd(cnt + e23.w, 1);
  int r7 = atomicAdd(cnt + e23.z, 1);
  uint4 pk;
  pk.x = (unsigned)r0 | ((unsigned)r1 << 16);
  pk.y = (unsigned)r2 | ((unsigned)r3 << 16);
  pk.z = (unsigned)r4 | ((unsigned)r5 << 16);
  pk.w = (unsigned)r6 | ((unsigned)r7 << 16);
  reinterpret_cast<uint4*>(rank)[t] = pk;  // coalesced 16B
}

// ---- hierarchical scan A
__global__ __launch_bounds__(1024) void k_scanA(const int* __restrict__ cnt,
                                                int* __restrict__ offs,
                                                int* __restrict__ bsum, int n) {
  __shared__ int sd[1024];
  const int tid = threadIdx.x;
  const int i = blockIdx.x * 1024 + tid;
  int v = (i < n) ? cnt[i] : 0;
  sd[tid] = v;
  __syncthreads();
  for (int off = 1; off < 1024; off <<= 1) {
    int t = (tid >= off) ? sd[tid - off] : 0;
    __syncthreads();
    sd[tid] += t;
    __syncthreads();
  }
  if (i < n) offs[i] = sd[tid] - v;
  if (tid == 1023) bsum[blockIdx.x] = sd[1023];
}

// ---- scan B
__global__ __launch_bounds__(128) void k_scanB(int* __restrict__ bsum,
                                               int* __restrict__ offs, int n, int nb) {
  __shared__ int sd[128];
  const int tid = threadIdx.x;
  int v = (tid < nb) ? bsum[tid] : 0;
  sd[tid] = v;
  __syncthreads();
  for (int off = 1; off < 128; off <<= 1) {
    int t = (tid >= off) ? sd[tid - off] : 0;
    __syncthreads();
    sd[tid] += t;
    __syncthreads();
  }
  if (tid < nb) bsum[tid] = sd[tid] - v;
  if (tid == 127) offs[n] = sd[127];
}

// ---- scan C
__global__ __launch_bounds__(256) void k_scanC(int* __restrict__ offs,
                                               const int* __restrict__ bsum, int n) {
  int i = blockIdx.x * 256 + threadIdx.x;
  if (i < n) offs[i] += bsum[i >> 10];
}

// ---- place pass: no atomics; slot = offs[node] + rank
__global__ __launch_bounds__(256) void k_place(const int* __restrict__ edges,
                                               const ushort* __restrict__ rank,
                                               const int* __restrict__ offs,
                                               int* __restrict__ nbr, int nq) {
  int t = blockIdx.x * 256 + threadIdx.x;
  if (t >= nq) return;
  const int4* ep = reinterpret_cast<const int4*>(edges + 8 * t);
  int4 e01 = ep[0], e23 = ep[1];
  uint4 pk = reinterpret_cast<const uint4*>(rank)[t];
  int o0 = offs[e01.y], o1 = offs[e01.x], o2 = offs[e01.w], o3 = offs[e01.z];
  int o4 = offs[e23.y], o5 = offs[e23.x], o6 = offs[e23.w], o7 = offs[e23.z];
  nbr[o0 + (pk.x & 0xffff)] = e01.x;
  nbr[o1 + (pk.x >> 16)]    = e01.y;
  nbr[o2 + (pk.y & 0xffff)] = e01.z;
  nbr[o3 + (pk.y >> 16)]    = e01.w;
  nbr[o4 + (pk.z & 0xffff)] = e23.x;
  nbr[o5 + (pk.z >> 16)]    = e23.y;
  nbr[o6 + (pk.w & 0xffff)] = e23.z;
  nbr[o7 + (pk.w >> 16)]    = e23.w;
}

// W staged transposed+padded: wT[j*68+k] = W[k*64+j]
__device__ __forceinline__ void stage_w(const float* __restrict__ W, float* wT) {
  for (int i = threadIdx.x; i < 4096; i += 256) {
    int k = i >> 6, j = i & 63;
    wT[j * 68 + k] = W[i];
  }
}

// ---- gemm2: base = h@W0+b0 (f32), msg = bf16(h@W1+b1).
// Coalesced 8-row register staging -> wave-private LDS -> broadcast ds_read.
// k4 loop is deliberately NOT unrolled: rolled loop keeps the W LDS reads
// non-invariant, preventing LICM from hoisting 32 float4s into registers
// (R8/R9 failure: 200-256 VGPR + scratch spills).
__global__ __launch_bounds__(256) void k_gemm2(
    const float* __restrict__ h, const float* __restrict__ W0,
    const float* __restrict__ b0, const float* __restrict__ W1,
    const float* __restrict__ b1, float* __restrict__ base,
    __hip_bfloat16* __restrict__ msg, int nrows) {
  __shared__ float w0T[64 * 68];
  __shared__ float w1T[64 * 68];
  __shared__ float rbuf[4][RB * 64];  // 8 KB: wave-private row tiles
  stage_w(W0, w0T);
  stage_w(W1, w1T);
  __syncthreads();
  const int lane = threadIdx.x & 63;
  const int wv = threadIdx.x >> 6;
  const int wid = (blockIdx.x * 256 + threadIdx.x) >> 6;
  const int nw = (gridDim.x * 256) >> 6;
  const float bv0 = b0[lane], bv1 = b1[lane];
  const float4* wl0 = reinterpret_cast<const float4*>(&w0T[lane * 68]);
  const float4* wl1 = reinterpret_cast<const float4*>(&w1T[lane * 68]);
  float* myrows = rbuf[wv];

  const int chunk = (nrows + nw - 1) / nw;
  const int r0 = wid * chunk;
  const int r1 = min(r0 + chunk, nrows);
  if (r0 >= nrows) return;

  // prologue: coalesced load of first batch (1 instr = 1 full row)
  float st[RB];
#pragma unroll
  for (int rr = 0; rr < RB; ++rr) {
    int r = min(r0 + rr, nrows - 1);
    st[rr] = h[(size_t)r * 64 + lane];
  }
  for (int rb = r0; rb < r1; rb += RB) {
    // park staged rows in LDS (wave-private; no barrier needed)
#pragma unroll
    for (int rr = 0; rr < RB; ++rr) myrows[rr * 64 + lane] = st[rr];
    // issue next batch's loads early (hide HBM/L2 latency under compute)
    const int nb = rb + RB;
    if (nb < r1) {
#pragma unroll
      for (int rr = 0; rr < RB; ++rr) {
        int r = min(nb + rr, nrows - 1);
        st[rr] = h[(size_t)r * 64 + lane];
      }
    }
    float a0[RB], a1[RB];
#pragma unroll
    for (int rr = 0; rr < RB; ++rr) { a0[rr] = bv0; a1[rr] = bv1; }
#pragma unroll 1  // CRITICAL: rolled k4 -> W reads stay in LDS (no LICM blowup)
    for (int k4 = 0; k4 < 16; ++k4) {
      const float4 v0 = wl0[k4];  // per-lane W column slice (reused 8 rows)
      const float4 v1 = wl1[k4];
#pragma unroll
      for (int rr = 0; rr < RB; ++rr) {
        float4 hv = *reinterpret_cast<const float4*>(&myrows[rr * 64 + k4 * 4]);
        a0[rr] = fmaf(hv.x, v0.x, a0[rr]); a1[rr] = fmaf(hv.x, v1.x, a1[rr]);
        a0[rr] = fmaf(hv.y, v0.y, a0[rr]); a1[rr] = fmaf(hv.y, v1.y, a1[rr]);
        a0[rr] = fmaf(hv.z, v0.z, a0[rr]); a1[rr] = fmaf(hv.z, v1.z, a1[rr]);
        a0[rr] = fmaf(hv.w, v0.w, a0[rr]); a1[rr] = fmaf(hv.w, v1.w, a1[rr]);
      }
    }
#pragma unroll
    for (int rr = 0; rr < RB; ++rr) {
      int r = rb + rr;
      if (r < r1) {
        base[(size_t)r * 64 + lane] = a0[rr];
        msg[(size_t)r * 64 + lane] = __float2bfloat16(a1[rr]);
      }
    }
  }
}

// ---- gather: half-wave pair loads (2 neighbor rows per instruction)
template <bool LN>
__global__ __launch_bounds__(256) void k_agg(
    const float* __restrict__ base, const __hip_bfloat16* __restrict__ msg,
    const int* __restrict__ offs, const int* __restrict__ nbr,
    const float* __restrict__ gamma, const float* __restrict__ beta,
    float* __restrict__ out, int nrows) {
  const int lane = threadIdx.x & 63;
  const int half = lane >> 5;
  const int c = lane & 31;
  const int wid = (blockIdx.x * 256 + threadIdx.x) >> 6;
  const int nw = (gridDim.x * 256) >> 6;
  float gm = 1.0f, bt = 0.0f;
  if (LN) { gm = gamma[lane]; bt = beta[lane]; }
  const unsigned* msg32 = reinterpret_cast<const unsigned*>(msg);
  for (int r = wid; r < nrows; r += nw) {
    const int n0 = offs[r], n1 = offs[r + 1];
    const float bval = base[(size_t)r * 64 + lane];
    float agx = 0.0f, agy = 0.0f;
    int j = n0;
    for (; j + 32 <= n1; j += 32) {
      int idx[16];
#pragma unroll
      for (int u = 0; u < 16; ++u) idx[u] = nbr[j + 2 * u + half];
      unsigned mv[16];
#pragma unroll
      for (int u = 0; u < 16; ++u) mv[u] = msg32[(idx[u] << 5) + c];
#pragma unroll
      for (int u = 0; u < 16; ++u) { agx += bflo(mv[u]); agy += bfhi(mv[u]); }
    }
    for (; j + 8 <= n1; j += 8) {
      int idx[4];
#pragma unroll
      for (int u = 0; u < 4; ++u) idx[u] = nbr[j + 2 * u + half];
      unsigned mv[4];
#pragma unroll
      for (int u = 0; u < 4; ++u) mv[u] = msg32[(idx[u] << 5) + c];
#pragma unroll
      for (int u = 0; u < 4; ++u) { agx += bflo(mv[u]); agy += bfhi(mv[u]); }
    }
    for (; j + 2 <= n1; j += 2) {
      unsigned mv = msg32[(nbr[j + half] << 5) + c];
      agx += bflo(mv); agy += bfhi(mv);
    }
    agx += __shfl_xor(agx, 32, 64);
    agy += __shfl_xor(agy, 32, 64);
    float tx = __shfl(agx, lane >> 1, 64);
    float ty = __shfl(agy, lane >> 1, 64);
    float ag = (lane & 1) ? ty : tx;
    for (; j < n1; ++j)
      ag += __bfloat162float(msg[((int)nbr[j] << 6) + lane]);
    const float rdeg = 1.0f / fmaxf((float)(n1 - n0), 1.0f);
    float val = fmaf(ag, rdeg, bval);
    if (LN) {
      float s = val;
#pragma unroll
      for (int off = 32; off > 0; off >>= 1) s += __shfl_xor(s, off, 64);
      const float mu = s * (1.0f / 64.0f);
      const float dv = val - mu;
      float v2 = dv * dv;
#pragma unroll
      for (int off = 32; off > 0; off >>= 1) v2 += __shfl_xor(v2, off, 64);
      const float var = v2 * (1.0f / 64.0f);
      val = fmaxf(fmaf(dv * rsqrtf(var + 1e-5f), gm, bt), 0.0f);
    }
    out[(size_t)r * 64 + lane] = val;
  }
}

extern "C" void kernel_launch(void* const* d_in, const int* in_sizes, int n_in,
                              void* d_out, int out_size, void* d_ws, size_t ws_size,
                              hipStream_t stream) {
  const float* vert = (const float*)d_in[0];
  const int* edges = (const int*)d_in[1];
  const float* W0 = (const float*)d_in[2];
  const float* b0 = (const float*)d_in[3];
  const float* W1 = (const float*)d_in[4];
  const float* b1 = (const float*)d_in[5];
  const float* lng = (const float*)d_in[6];
  const float* lnb = (const float*)d_in[7];
  float* base = (float*)d_out;  // base buffer lives in d_out all layers

  const size_t HB = (size_t)NN * D_ * sizeof(float);  // 25.6 MB
  float* hbuf = (float*)d_ws;
  int* nbr = (int*)((char*)d_ws + HB);  // 12.8 MB
  char* msgreg = (char*)d_ws + HB + (size_t)2 * NE * 4;  // 12.8 MB region
  __hip_bfloat16* msg = (__hip_bfloat16*)msgreg;
  // CSR-build temporaries alias the msg region (dead before gemm2 writes msg)
  ushort* rank = (ushort*)msgreg;                      // 6.4 MB
  int* cnt = (int*)(msgreg + (size_t)2 * NE * 2);      // 400 KB
  int* bsum = cnt + NN;
  int* offs = (int*)((char*)d_ws + HB + (size_t)2 * NE * 4 + HB / 2);  // persistent

  const int NQ4 = NE / 4;

  // ---- CSR build: rank-merge (one atomic pass, one atomic-free place pass)
  hipMemsetAsync(cnt, 0, NN * sizeof(int), stream);
  k_rank<<<(NQ4 + 255) / 256, 256, 0, stream>>>(edges, cnt, rank, NQ4);
  k_scanA<<<NBLK, 1024, 0, stream>>>(cnt, offs, bsum, NN);
  k_scanB<<<1, 128, 0, stream>>>(bsum, offs, NN, NBLK);
  k_scanC<<<(NN + 255) / 256, 256, 0, stream>>>(offs, bsum, NN);
  k_place<<<(NQ4 + 255) / 256, 256, 0, stream>>>(edges, rank, offs, nbr, NQ4);

  const int GB = 2048;   // agg grid
  const int GG = 1024;   // gemm2 grid: 4096 waves (~full residency at 4/SIMD)

  for (int l = 0; l < 3; ++l) {
    const float* hcur = (l == 0) ? vert : hbuf;
    k_gemm2<<<GG, 256, 0, stream>>>(hcur, W0 + l * 4096, b0 + l * 64,
                                    W1 + l * 4096, b1 + l * 64, base, msg, NN);
    if (l < 2) {
      k_agg<true><<<GB, 256, 0, stream>>>(base, msg, offs, nbr,
                                          lng + l * 64, lnb + l * 64, hbuf, NN);
    } else {
      k_agg<false><<<GB, 256, 0, stream>>>(base, msg, offs, nbr,
                                           nullptr, nullptr, base, NN);
    }
  }
}

// Round 11
// 439.611 us; speedup vs baseline: 3.2499x; 1.3055x over previous
//
#include <hip/hip_runtime.h>
#include <hip/hip_bf16.h>

constexpr int D_ = 64;
constexpr int NN = 100000;
constexpr int NE = 1600000;
constexpr int RB = 8;        // rows per wave-batch in gemm2

// ---- sort-CSR parameters
constexpr int BUCK_SH = 7;                         // 128 nodes per bucket
constexpr int NBUCK = (NN + 127) >> BUCK_SH;       // 782
constexpr int NB1 = 256;                           // S1 grid
constexpr int NQ4 = NE / 4;                        // 400000 quads
constexpr int QPB = (NQ4 + NB1 - 1) / NB1;         // 1563 quads/block
constexpr int SCN = NBUCK * NB1;                   // 200192 count entries
constexpr int SCB = (SCN + 1023) / 1024;           // 196 scan blocks

__device__ __forceinline__ float bflo(unsigned v) { return __uint_as_float(v << 16); }
__device__ __forceinline__ float bfhi(unsigned v) { return __uint_as_float(v & 0xffff0000u); }

// ---- S1A: per-block LDS histogram of endpoint buckets (no global atomics)
__global__ __launch_bounds__(256) void k_s1count(const int* __restrict__ edges,
                                                 int* __restrict__ cnts) {
  __shared__ int hist[NBUCK];
  for (int i = threadIdx.x; i < NBUCK; i += 256) hist[i] = 0;
  __syncthreads();
  const int q0 = blockIdx.x * QPB;
  const int q1 = min(q0 + QPB, NQ4);
  for (int q = q0 + (int)threadIdx.x; q < q1; q += 256) {
    const int4* ep = reinterpret_cast<const int4*>(edges + 8 * q);
    int4 a = ep[0], b = ep[1];
    atomicAdd(&hist[a.x >> BUCK_SH], 1);
    atomicAdd(&hist[a.y >> BUCK_SH], 1);
    atomicAdd(&hist[a.z >> BUCK_SH], 1);
    atomicAdd(&hist[a.w >> BUCK_SH], 1);
    atomicAdd(&hist[b.x >> BUCK_SH], 1);
    atomicAdd(&hist[b.y >> BUCK_SH], 1);
    atomicAdd(&hist[b.z >> BUCK_SH], 1);
    atomicAdd(&hist[b.w >> BUCK_SH], 1);
  }
  __syncthreads();
  for (int i = threadIdx.x; i < NBUCK; i += 256)
    cnts[i * NB1 + blockIdx.x] = hist[i];  // bucket-major for linear scan
}

// ---- hierarchical scan A (1024-wide blocks)
__global__ __launch_bounds__(1024) void k_scanA(const int* __restrict__ cnt,
                                                int* __restrict__ oscan,
                                                int* __restrict__ bsum, int n) {
  __shared__ int sd[1024];
  const int tid = threadIdx.x;
  const int i = blockIdx.x * 1024 + tid;
  int v = (i < n) ? cnt[i] : 0;
  sd[tid] = v;
  __syncthreads();
  for (int off = 1; off < 1024; off <<= 1) {
    int t = (tid >= off) ? sd[tid - off] : 0;
    __syncthreads();
    sd[tid] += t;
    __syncthreads();
  }
  if (i < n) oscan[i] = sd[tid] - v;
  if (tid == 1023) bsum[blockIdx.x] = sd[1023];
}

// ---- scan B: single 256-thread block scans block totals (exclusive, in place)
__global__ __launch_bounds__(256) void k_scanB(int* __restrict__ bsum, int nb) {
  __shared__ int sd[256];
  const int tid = threadIdx.x;
  int v = (tid < nb) ? bsum[tid] : 0;
  sd[tid] = v;
  __syncthreads();
  for (int off = 1; off < 256; off <<= 1) {
    int t = (tid >= off) ? sd[tid - off] : 0;
    __syncthreads();
    sd[tid] += t;
    __syncthreads();
  }
  if (tid < nb) bsum[tid] = sd[tid] - v;
}

// ---- scan C: add block base
__global__ __launch_bounds__(256) void k_scanC(int* __restrict__ oscan,
                                               const int* __restrict__ bsum, int n) {
  int i = blockIdx.x * 256 + threadIdx.x;
  if (i < n) oscan[i] += bsum[i >> 10];
}

// ---- S1B: scatter items into bucket-sorted array via LDS cursors.
// item = (key&127)<<17 | other  (7+17 bits). Same block->quad map as S1A.
__global__ __launch_bounds__(256) void k_s1scatter(const int* __restrict__ edges,
                                                   const int* __restrict__ sscan,
                                                   unsigned* __restrict__ items) {
  __shared__ int cur[NBUCK];
  for (int i = threadIdx.x; i < NBUCK; i += 256)
    cur[i] = sscan[i * NB1 + blockIdx.x];
  __syncthreads();
  const int q0 = blockIdx.x * QPB;
  const int q1 = min(q0 + QPB, NQ4);
  for (int q = q0 + (int)threadIdx.x; q < q1; q += 256) {
    const int4* ep = reinterpret_cast<const int4*>(edges + 8 * q);
    int4 a = ep[0], b = ep[1];
    int p;
    p = atomicAdd(&cur[a.y >> BUCK_SH], 1); items[p] = ((unsigned)(a.y & 127) << 17) | (unsigned)a.x;
    p = atomicAdd(&cur[a.x >> BUCK_SH], 1); items[p] = ((unsigned)(a.x & 127) << 17) | (unsigned)a.y;
    p = atomicAdd(&cur[a.w >> BUCK_SH], 1); items[p] = ((unsigned)(a.w & 127) << 17) | (unsigned)a.z;
    p = atomicAdd(&cur[a.z >> BUCK_SH], 1); items[p] = ((unsigned)(a.z & 127) << 17) | (unsigned)a.w;
    p = atomicAdd(&cur[b.y >> BUCK_SH], 1); items[p] = ((unsigned)(b.y & 127) << 17) | (unsigned)b.x;
    p = atomicAdd(&cur[b.x >> BUCK_SH], 1); items[p] = ((unsigned)(b.x & 127) << 17) | (unsigned)b.y;
    p = atomicAdd(&cur[b.w >> BUCK_SH], 1); items[p] = ((unsigned)(b.w & 127) << 17) | (unsigned)b.z;
    p = atomicAdd(&cur[b.z >> BUCK_SH], 1); items[p] = ((unsigned)(b.z & 127) << 17) | (unsigned)b.w;
  }
}

// ---- S2: one block per bucket -> local histogram+scan -> offs + nbr placement
__global__ __launch_bounds__(256) void k_s2build(const unsigned* __restrict__ items,
                                                 const int* __restrict__ sscan,
                                                 int* __restrict__ offs,
                                                 int* __restrict__ nbr) {
  const int b = blockIdx.x;
  const int lo = b << BUCK_SH;
  __shared__ int hist[128], scn[128];
  __shared__ int sbase, send;
  if (threadIdx.x == 0) {
    sbase = sscan[b * NB1];
    send = (b + 1 < NBUCK) ? sscan[(b + 1) * NB1] : 2 * NE;
  }
  if (threadIdx.x < 128) hist[threadIdx.x] = 0;
  __syncthreads();
  const int i0 = sbase, i1 = send;
  for (int i = i0 + (int)threadIdx.x; i < i1; i += 256)
    atomicAdd(&hist[items[i] >> 17], 1);
  __syncthreads();
  if (threadIdx.x < 128) scn[threadIdx.x] = hist[threadIdx.x];
  __syncthreads();
  for (int off = 1; off < 128; off <<= 1) {
    int t = (threadIdx.x < 128 && (int)threadIdx.x >= off) ? scn[threadIdx.x - off] : 0;
    __syncthreads();
    if (threadIdx.x < 128) scn[threadIdx.x] += t;
    __syncthreads();
  }
  if (threadIdx.x < 128) {
    int node = lo + threadIdx.x;
    int ex = sbase + scn[threadIdx.x] - hist[threadIdx.x];  // exclusive + bucket base
    if (node < NN) offs[node] = ex;
    hist[threadIdx.x] = ex;  // becomes the placement cursor
  }
  __syncthreads();
  for (int i = i0 + (int)threadIdx.x; i < i1; i += 256) {
    unsigned it = items[i];
    int pos = atomicAdd(&hist[it >> 17], 1);
    nbr[pos] = (int)(it & 0x1FFFFu);
  }
  if (b == 0 && threadIdx.x == 0) offs[NN] = 2 * NE;
}

// W staged transposed+padded: wT[j*68+k] = W[k*64+j]
__device__ __forceinline__ void stage_w(const float* __restrict__ W, float* wT) {
  for (int i = threadIdx.x; i < 4096; i += 256) {
    int k = i >> 6, j = i & 63;
    wT[j * 68 + k] = W[i];
  }
}

// ---- gemm2: base = h@W0+b0 (f32), msg = bf16(h@W1+b1).
// k4 loop deliberately rolled (#pragma unroll 1): keeps W reads in LDS,
// prevents LICM from hoisting 32 float4s into registers (R8/R9: 200-256 VGPR).
__global__ __launch_bounds__(256) void k_gemm2(
    const float* __restrict__ h, const float* __restrict__ W0,
    const float* __restrict__ b0, const float* __restrict__ W1,
    const float* __restrict__ b1, float* __restrict__ base,
    __hip_bfloat16* __restrict__ msg, int nrows) {
  __shared__ float w0T[64 * 68];
  __shared__ float w1T[64 * 68];
  __shared__ float rbuf[4][RB * 64];
  stage_w(W0, w0T);
  stage_w(W1, w1T);
  __syncthreads();
  const int lane = threadIdx.x & 63;
  const int wv = threadIdx.x >> 6;
  const int wid = (blockIdx.x * 256 + threadIdx.x) >> 6;
  const int nw = (gridDim.x * 256) >> 6;
  const float bv0 = b0[lane], bv1 = b1[lane];
  const float4* wl0 = reinterpret_cast<const float4*>(&w0T[lane * 68]);
  const float4* wl1 = reinterpret_cast<const float4*>(&w1T[lane * 68]);
  float* myrows = rbuf[wv];

  const int chunk = (nrows + nw - 1) / nw;
  const int r0 = wid * chunk;
  const int r1 = min(r0 + chunk, nrows);
  if (r0 >= nrows) return;

  float st[RB];
#pragma unroll
  for (int rr = 0; rr < RB; ++rr) {
    int r = min(r0 + rr, nrows - 1);
    st[rr] = h[(size_t)r * 64 + lane];
  }
  for (int rb = r0; rb < r1; rb += RB) {
#pragma unroll
    for (int rr = 0; rr < RB; ++rr) myrows[rr * 64 + lane] = st[rr];
    const int nb = rb + RB;
    if (nb < r1) {
#pragma unroll
      for (int rr = 0; rr < RB; ++rr) {
        int r = min(nb + rr, nrows - 1);
        st[rr] = h[(size_t)r * 64 + lane];
      }
    }
    float a0[RB], a1[RB];
#pragma unroll
    for (int rr = 0; rr < RB; ++rr) { a0[rr] = bv0; a1[rr] = bv1; }
#pragma unroll 1
    for (int k4 = 0; k4 < 16; ++k4) {
      const float4 v0 = wl0[k4];
      const float4 v1 = wl1[k4];
#pragma unroll
      for (int rr = 0; rr < RB; ++rr) {
        float4 hv = *reinterpret_cast<const float4*>(&myrows[rr * 64 + k4 * 4]);
        a0[rr] = fmaf(hv.x, v0.x, a0[rr]); a1[rr] = fmaf(hv.x, v1.x, a1[rr]);
        a0[rr] = fmaf(hv.y, v0.y, a0[rr]); a1[rr] = fmaf(hv.y, v1.y, a1[rr]);
        a0[rr] = fmaf(hv.z, v0.z, a0[rr]); a1[rr] = fmaf(hv.z, v1.z, a1[rr]);
        a0[rr] = fmaf(hv.w, v0.w, a0[rr]); a1[rr] = fmaf(hv.w, v1.w, a1[rr]);
      }
    }
#pragma unroll
    for (int rr = 0; rr < RB; ++rr) {
      int r = rb + rr;
      if (r < r1) {
        base[(size_t)r * 64 + lane] = a0[rr];
        msg[(size_t)r * 64 + lane] = __float2bfloat16(a1[rr]);
      }
    }
  }
}

// ---- gather: half-wave pair loads (2 neighbor rows per instruction)
template <bool LN>
__global__ __launch_bounds__(256) void k_agg(
    const float* __restrict__ base, const __hip_bfloat16* __restrict__ msg,
    const int* __restrict__ offs, const int* __restrict__ nbr,
    const float* __restrict__ gamma, const float* __restrict__ beta,
    float* __restrict__ out, int nrows) {
  const int lane = threadIdx.x & 63;
  const int half = lane >> 5;
  const int c = lane & 31;
  const int wid = (blockIdx.x * 256 + threadIdx.x) >> 6;
  const int nw = (gridDim.x * 256) >> 6;
  float gm = 1.0f, bt = 0.0f;
  if (LN) { gm = gamma[lane]; bt = beta[lane]; }
  const unsigned* msg32 = reinterpret_cast<const unsigned*>(msg);
  for (int r = wid; r < nrows; r += nw) {
    const int n0 = offs[r], n1 = offs[r + 1];
    const float bval = base[(size_t)r * 64 + lane];
    float agx = 0.0f, agy = 0.0f;
    int j = n0;
    for (; j + 32 <= n1; j += 32) {
      int idx[16];
#pragma unroll
      for (int u = 0; u < 16; ++u) idx[u] = nbr[j + 2 * u + half];
      unsigned mv[16];
#pragma unroll
      for (int u = 0; u < 16; ++u) mv[u] = msg32[(idx[u] << 5) + c];
#pragma unroll
      for (int u = 0; u < 16; ++u) { agx += bflo(mv[u]); agy += bfhi(mv[u]); }
    }
    for (; j + 8 <= n1; j += 8) {
      int idx[4];
#pragma unroll
      for (int u = 0; u < 4; ++u) idx[u] = nbr[j + 2 * u + half];
      unsigned mv[4];
#pragma unroll
      for (int u = 0; u < 4; ++u) mv[u] = msg32[(idx[u] << 5) + c];
#pragma unroll
      for (int u = 0; u < 4; ++u) { agx += bflo(mv[u]); agy += bfhi(mv[u]); }
    }
    for (; j + 2 <= n1; j += 2) {
      unsigned mv = msg32[(nbr[j + half] << 5) + c];
      agx += bflo(mv); agy += bfhi(mv);
    }
    agx += __shfl_xor(agx, 32, 64);
    agy += __shfl_xor(agy, 32, 64);
    float tx = __shfl(agx, lane >> 1, 64);
    float ty = __shfl(agy, lane >> 1, 64);
    float ag = (lane & 1) ? ty : tx;
    for (; j < n1; ++j)
      ag += __bfloat162float(msg[((int)nbr[j] << 6) + lane]);
    const float rdeg = 1.0f / fmaxf((float)(n1 - n0), 1.0f);
    float val = fmaf(ag, rdeg, bval);
    if (LN) {
      float s = val;
#pragma unroll
      for (int off = 32; off > 0; off >>= 1) s += __shfl_xor(s, off, 64);
      const float mu = s * (1.0f / 64.0f);
      const float dv = val - mu;
      float v2 = dv * dv;
#pragma unroll
      for (int off = 32; off > 0; off >>= 1) v2 += __shfl_xor(v2, off, 64);
      const float var = v2 * (1.0f / 64.0f);
      val = fmaxf(fmaf(dv * rsqrtf(var + 1e-5f), gm, bt), 0.0f);
    }
    out[(size_t)r * 64 + lane] = val;
  }
}

extern "C" void kernel_launch(void* const* d_in, const int* in_sizes, int n_in,
                              void* d_out, int out_size, void* d_ws, size_t ws_size,
                              hipStream_t stream) {
  const float* vert = (const float*)d_in[0];
  const int* edges = (const int*)d_in[1];
  const float* W0 = (const float*)d_in[2];
  const float* b0 = (const float*)d_in[3];
  const float* W1 = (const float*)d_in[4];
  const float* b1 = (const float*)d_in[5];
  const float* lng = (const float*)d_in[6];
  const float* lnb = (const float*)d_in[7];
  float* base = (float*)d_out;  // base lives in d_out every layer

  const size_t HB = (size_t)NN * D_ * sizeof(float);  // 25.6 MB
  float* hbuf = (float*)d_ws;                                  // persistent h
  int* nbr = (int*)((char*)d_ws + HB);                         // 12.8 MB persistent
  char* msgreg = (char*)d_ws + HB + (size_t)2 * NE * 4;        // 12.8 MB region
  __hip_bfloat16* msg = (__hip_bfloat16*)msgreg;
  unsigned* items = (unsigned*)msgreg;  // CSR build: 2*NE u32 = 12.8 MB (dead before msg)
  int* offs = (int*)((char*)d_ws + HB + (size_t)2 * NE * 4 + HB / 2);  // persistent
  // CSR scan temporaries live in d_out (dead before gemm2-L0 writes base)
  int* cnts = (int*)d_out;        // SCN ints
  int* sscan = cnts + SCN;        // SCN ints
  int* bsum = sscan + SCN;        // SCB ints

  // ---- CSR build: bucket sort, zero global atomics
  k_s1count<<<NB1, 256, 0, stream>>>(edges, cnts);
  k_scanA<<<SCB, 1024, 0, stream>>>(cnts, sscan, bsum, SCN);
  k_scanB<<<1, 256, 0, stream>>>(bsum, SCB);
  k_scanC<<<(SCN + 255) / 256, 256, 0, stream>>>(sscan, bsum, SCN);
  k_s1scatter<<<NB1, 256, 0, stream>>>(edges, sscan, items);
  k_s2build<<<NBUCK, 256, 0, stream>>>(items, sscan, offs, nbr);

  const int GB = 2048;   // agg grid
  const int GG = 1024;   // gemm2 grid

  for (int l = 0; l < 3; ++l) {
    const float* hcur = (l == 0) ? vert : hbuf;
    k_gemm2<<<GG, 256, 0, stream>>>(hcur, W0 + l * 4096, b0 + l * 64,
                                    W1 + l * 4096, b1 + l * 64, base, msg, NN);
    if (l < 2) {
      k_agg<true><<<GB, 256, 0, stream>>>(base, msg, offs, nbr,
                                          lng + l * 64, lnb + l * 64, hbuf, NN);
    } else {
      k_agg<false><<<GB, 256, 0, stream>>>(base, msg, offs, nbr,
                                           nullptr, nullptr, base, NN);
    }
  }
}